// Round 2
// baseline (387.462 us; speedup 1.0000x reference)
//
#include <hip/hip_runtime.h>
#include <hip/hip_bf16.h>

// Problem: tokens[b,n,t] = mask[b,n] ? (cat_feats[b,n,:] . W[t,:] + bias[t]) : 0
// cat_feats = [embeddings(3072) | vis(6) | bbox(4) | kpts(51)]  => K = 3133
// M = B*N = 16384, T = 256.
// Strategy: bf16 MFMA GEMM (threshold 5.9e-2 allows bf16 inputs, f32 accum).
//  - prepack W -> bf16 [256][3136] (padded, aligned rows) in ws
//  - prepack extras -> f32 [16384][64] (padded) in ws -> uniform K loop (49 steps of 64)
//  - main: BM=64 x BT=128, 4 waves (32x64 each), double-buffered LDS (pad stride 72),
//    reg-staged f32->bf16 conversion, mask-skipped A loads, masked epilogue + bias.
// R1 fix: feats_masks (jnp.bool_) is delivered as int32 by the harness
//         ("integer -> const int*"), NOT 1-byte bool. Reading it as uchar zeroed
//         ~75% of valid rows (absmax == max|ref| signature).

#define TOKENS   16384
#define EMB      3072
#define KF       3133
#define KP       3136
#define TDIM     256
#define BKS      64
#define NSTEP    49      // 48 embedding steps + 1 extras step
#define BM       64
#define BT       128
#define SP       72      // padded LDS row stride (bf16 elems): 144B -> 2-way conflicts only

typedef __attribute__((ext_vector_type(8))) short bf16x8;
typedef __attribute__((ext_vector_type(4))) float f32x4;

__device__ __forceinline__ unsigned int f2bf(float f) {
  __hip_bfloat16 h = __float2bfloat16(f);
  unsigned short u;
  __builtin_memcpy(&u, &h, 2);
  return (unsigned int)u;
}
__device__ __forceinline__ unsigned int pack2(float a, float b) {
  return f2bf(a) | (f2bf(b) << 16);
}

__global__ void pack_w_kernel(const float* __restrict__ W, unsigned short* __restrict__ wq) {
  int i = blockIdx.x * 256 + threadIdx.x;   // over TDIM*KP = 802816
  if (i >= TDIM * KP) return;
  int t = i / KP;
  int k = i - t * KP;
  float v = (k < KF) ? W[(size_t)t * KF + k] : 0.f;
  __hip_bfloat16 h = __float2bfloat16(v);
  unsigned short u; __builtin_memcpy(&u, &h, 2);
  wq[i] = u;
}

__global__ void pack_ext_kernel(const float* __restrict__ vis,
                                const float* __restrict__ bbox,
                                const float* __restrict__ kpt,
                                float* __restrict__ ext) {
  int i = blockIdx.x * 256 + threadIdx.x;   // over TOKENS*64 = 1048576
  int bn = i >> 6;
  int j  = i & 63;
  float v = 0.f;
  if (j < 6)       v = vis[bn * 6 + j];
  else if (j < 10) v = bbox[bn * 4 + (j - 6)];
  else if (j < 61) v = kpt[bn * 51 + (j - 10)];
  ext[i] = v;
}

__global__ __launch_bounds__(256, 2)
void linproj_kernel(const float* __restrict__ emb,
                    const int* __restrict__ mask,          // int32 per harness contract
                    const unsigned short* __restrict__ wq,
                    const float* __restrict__ ext,
                    const float* __restrict__ bias,
                    float* __restrict__ out) {
  __shared__ unsigned short lds[2 * BM * SP + 2 * BT * SP];  // 55296 B

  const int tid = threadIdx.x;
  const int bid = blockIdx.x;
  // swizzle: blocks 16a..16a+7 -> ttile0 of mtiles 8a..8a+7 (XCDs 0..7),
  //          blocks 16a+8..16a+15 -> ttile1 of the SAME mtiles on the SAME XCDs
  // so the A-tile's second read hits that XCD's L2.
  const int mtile = ((bid >> 4) << 3) | (bid & 7);
  const int ttile = (bid >> 3) & 1;
  const int mBase = mtile * BM;
  const int tBase = ttile * BT;

  // staging mapping: 8 threads per row, 8 elems (16B bf16 / 32B f32) each
  const int srow = tid >> 3;        // 0..31
  const int scol = (tid & 7) * 8;   // 0..56

  // compute mapping
  const int lane = tid & 63;
  const int wid  = tid >> 6;        // 0..3
  const int wm   = (wid >> 1) * 32; // wave M offset
  const int wt   = (wid & 1) * 64;  // wave T offset
  const int lr   = lane & 15;
  const int lk   = lane >> 4;       // 0..3

  // hoisted per-thread staging state
  bool mk[2];
  const float* pA[2];
  const float* pE[2];
  const unsigned short* pW[4];
#pragma unroll
  for (int it = 0; it < 2; ++it) {
    int bn = mBase + srow + it * 32;
    mk[it] = (mask[bn] != 0);
    pA[it] = emb + (size_t)bn * EMB + scol;
    pE[it] = ext + (size_t)bn * BKS + scol;
  }
#pragma unroll
  for (int it = 0; it < 4; ++it) {
    int tg = tBase + srow + it * 32;
    pW[it] = wq + (size_t)tg * KP + scol;
  }

  f32x4 acc[2][4];
#pragma unroll
  for (int m = 0; m < 2; ++m)
#pragma unroll
    for (int t = 0; t < 4; ++t)
      acc[m][t] = (f32x4){0.f, 0.f, 0.f, 0.f};

  float4 fa[2][2];
  uint4  rwv[4];

  auto stage = [&](int s) {
#pragma unroll
    for (int it = 0; it < 2; ++it) {
      if (mk[it]) {
        const float* p = (s < NSTEP - 1) ? (pA[it] + s * BKS) : pE[it];
        fa[it][0] = *(const float4*)p;
        fa[it][1] = *(const float4*)(p + 4);
      } else {
        fa[it][0] = make_float4(0.f, 0.f, 0.f, 0.f);
        fa[it][1] = make_float4(0.f, 0.f, 0.f, 0.f);
      }
    }
#pragma unroll
    for (int it = 0; it < 4; ++it)
      rwv[it] = *(const uint4*)(pW[it] + s * BKS);
  };

  auto commit = [&](int b) {
    unsigned short* la = &lds[b * (BM * SP)];
    unsigned short* lw = &lds[2 * (BM * SP) + b * (BT * SP)];
#pragma unroll
    for (int it = 0; it < 2; ++it) {
      uint4 v;
      v.x = pack2(fa[it][0].x, fa[it][0].y);
      v.y = pack2(fa[it][0].z, fa[it][0].w);
      v.z = pack2(fa[it][1].x, fa[it][1].y);
      v.w = pack2(fa[it][1].z, fa[it][1].w);
      *(uint4*)&la[(srow + it * 32) * SP + scol] = v;
    }
#pragma unroll
    for (int it = 0; it < 4; ++it)
      *(uint4*)&lw[(srow + it * 32) * SP + scol] = rwv[it];
  };

  auto compute = [&](int b) {
    const unsigned short* la = &lds[b * (BM * SP)];
    const unsigned short* lw = &lds[2 * (BM * SP) + b * (BT * SP)];
#pragma unroll
    for (int kk = 0; kk < 2; ++kk) {
      const int col = kk * 32 + lk * 8;
      bf16x8 a0 = *(const bf16x8*)&la[(wm + lr) * SP + col];
      bf16x8 a1 = *(const bf16x8*)&la[(wm + 16 + lr) * SP + col];
#pragma unroll
      for (int t = 0; t < 4; ++t) {
        bf16x8 bv = *(const bf16x8*)&lw[(wt + t * 16 + lr) * SP + col];
        acc[0][t] = __builtin_amdgcn_mfma_f32_16x16x32_bf16(a0, bv, acc[0][t], 0, 0, 0);
        acc[1][t] = __builtin_amdgcn_mfma_f32_16x16x32_bf16(a1, bv, acc[1][t], 0, 0, 0);
      }
    }
  };

  // prologue
  stage(0);
  commit(0);
  __syncthreads();

  int cur = 0;
#pragma unroll 1
  for (int s = 0; s < NSTEP; ++s) {
    const bool more = (s + 1) < NSTEP;
    if (more) stage(s + 1);   // issue next-tile global loads (latency hidden by MFMA)
    compute(cur);
    if (more) commit(cur ^ 1);
    __syncthreads();
    cur ^= 1;
  }

  // epilogue: C/D layout col=lane&15 (t), row=(lane>>4)*4+r (m)  [m89/m91]
#pragma unroll
  for (int m = 0; m < 2; ++m) {
#pragma unroll
    for (int tf = 0; tf < 4; ++tf) {
      const int t = tBase + wt + tf * 16 + lr;
      const float bv = bias[t];
#pragma unroll
      for (int r = 0; r < 4; ++r) {
        const int bn = mBase + wm + m * 16 + lk * 4 + r;
        const float o = (mask[bn] != 0) ? (acc[m][tf][r] + bv) : 0.f;
        out[(size_t)bn * TDIM + t] = o;
      }
    }
  }
}

extern "C" void kernel_launch(void* const* d_in, const int* in_sizes, int n_in,
                              void* d_out, int out_size, void* d_ws, size_t ws_size,
                              hipStream_t stream) {
  const float* emb   = (const float*)d_in[0];
  const float* vis   = (const float*)d_in[1];
  const float* bbox  = (const float*)d_in[2];
  const float* kpt   = (const float*)d_in[3];
  const int*   mask  = (const int*)d_in[4];   // jnp.bool_ -> int32 per harness contract
  const float* W     = (const float*)d_in[5];
  const float* bias  = (const float*)d_in[6];
  float* out = (float*)d_out;

  // ws layout: [ ext f32 16384*64 = 4 MB ][ W bf16 256*3136 = 1.57 MB ]
  float* ext          = (float*)d_ws;
  unsigned short* wq  = (unsigned short*)((char*)d_ws + (size_t)TOKENS * 64 * 4);

  pack_w_kernel  <<<(TDIM * KP + 255) / 256, 256, 0, stream>>>(W, wq);
  pack_ext_kernel<<<(TOKENS * 64) / 256,     256, 0, stream>>>(vis, bbox, kpt, ext);
  linproj_kernel <<<512, 256, 0, stream>>>(emb, mask, wq, ext, bias, out);
}

// Round 3
// 321.843 us; speedup vs baseline: 1.2039x; 1.2039x over previous
//
#include <hip/hip_runtime.h>
#include <hip/hip_bf16.h>

// tokens[bn,t] = mask[bn] ? (cat[bn,:]·W[t,:] + b[t]) : 0 ; M=16384, K=3133, T=256
// R3 restructure (R2 was latency-bound: MfmaUtil 6.3%, 7.9K cy/step):
//  - A (embeddings/ext, f32) -> wave-private reg fragments, direct from global,
//    mask-predicated loads, in-reg f32->bf16 cvt. No LDS, no ds_write for A.
//  - W -> prepacked bf16 as per-(ttile,step) 16KB linear LDS images with the
//    XOR bank-swizzle baked into GLOBAL layout (col' = col ^ ((row&7)<<3));
//    staged by 4x global_load_lds dwordx4 per wave per step (linear dest),
//    read back with the same XOR -> conflict-free ds_read_b128.
//  - ping-pong LDS (2x16KB), x2-unrolled loop (compile-time buffer index),
//    stage(s+1)+loadA(s+1) issued before compute(s).

#define TOKENS   16384
#define EMB      3072
#define KF       3133
#define TDIM     256
#define NSTEP    49      // 48 embedding steps + 1 extras step (ext[64])
#define BM       64
#define BT       128
#define WIMG     16384   // bytes per (ttile,step) W image: 128 rows x 64 cols bf16

typedef __attribute__((ext_vector_type(8))) short bf16x8;
typedef __attribute__((ext_vector_type(4))) float f32x4;

__device__ __forceinline__ unsigned int f2bf(float f) {
  __hip_bfloat16 h = __float2bfloat16(f);
  unsigned short u;
  __builtin_memcpy(&u, &h, 2);
  return (unsigned int)u;
}
__device__ __forceinline__ unsigned int pack2(float a, float b) {
  return f2bf(a) | (f2bf(b) << 16);
}
__device__ __forceinline__ bf16x8 cvt8(float4 a, float4 b) {
  union { unsigned int u[4]; bf16x8 v; } r;
  r.u[0] = pack2(a.x, a.y);
  r.u[1] = pack2(a.z, a.w);
  r.u[2] = pack2(b.x, b.y);
  r.u[3] = pack2(b.z, b.w);
  return r.v;
}

__device__ __forceinline__ void g2l16(const void* g, void* l) {
  // global (AS1) -> LDS (AS3) 16B async copy; LDS dest = wave-uniform base + lane*16
  __builtin_amdgcn_global_load_lds(
      (__attribute__((address_space(1))) void*)g,
      (__attribute__((address_space(3))) void*)l,
      16, 0, 0);
}

// W prepack: wq[tt][s][row][c'] (bf16), c' = c ^ ((row&7)<<3), row-major 128x64.
// This is byte-for-byte the linear LDS image stageW() DMAs in.
__global__ void pack_w_kernel(const float* __restrict__ W, unsigned short* __restrict__ wq) {
  int i = blockIdx.x * 256 + threadIdx.x;   // 2*49*8192 = 802816 total
  if (i >= 2 * NSTEP * 8192) return;
  int tt  = i / (NSTEP * 8192);
  int r   = i % (NSTEP * 8192);
  int s   = r >> 13;
  int e   = r & 8191;
  int row = e >> 6;
  int cs  = e & 63;
  int c   = cs ^ ((row & 7) << 3);          // un-swizzle to find source column
  int k   = s * 64 + c;
  int t   = tt * BT + row;
  float v = (k < KF) ? W[(size_t)t * KF + k] : 0.f;
  __hip_bfloat16 h = __float2bfloat16(v);
  unsigned short u; __builtin_memcpy(&u, &h, 2);
  wq[i] = u;
}

__global__ void pack_ext_kernel(const float* __restrict__ vis,
                                const float* __restrict__ bbox,
                                const float* __restrict__ kpt,
                                float* __restrict__ ext) {
  int i = blockIdx.x * 256 + threadIdx.x;   // TOKENS*64
  int bn = i >> 6;
  int j  = i & 63;
  float v = 0.f;
  if (j < 6)       v = vis[bn * 6 + j];
  else if (j < 10) v = bbox[bn * 4 + (j - 6)];
  else if (j < 61) v = kpt[bn * 51 + (j - 10)];
  ext[i] = v;
}

__global__ __launch_bounds__(256, 2)
void linproj_kernel(const float* __restrict__ emb,
                    const int* __restrict__ mask,
                    const unsigned short* __restrict__ wqp,
                    const float* __restrict__ ext,
                    const float* __restrict__ bias,
                    float* __restrict__ out) {
  __shared__ unsigned short ldsW[2 * 8192];   // 2 x 16KB ping-pong

  const int tid = threadIdx.x;
  const int bid = blockIdx.x;
  // XCD swizzle: both ttiles of an mtile land on the same XCD (A-tile L2 reuse)
  const int mtile = ((bid >> 4) << 3) | (bid & 7);
  const int ttile = (bid >> 3) & 1;
  const int mBase = mtile * BM;
  const int tBase = ttile * BT;

  const int lane = tid & 63;
  const int wid  = tid >> 6;        // 0..3
  const int wm   = (wid >> 1) * 32; // wave M offset
  const int wt   = (wid & 1) * 64;  // wave T offset
  const int lr   = lane & 15;
  const int lk   = lane >> 4;       // 0..3

  // ---- A (wave-private, reg-direct) ----
  const int row0 = mBase + wm + lr;
  const int row1 = row0 + 16;
  const bool m0 = (mask[row0] != 0);
  const bool m1 = (mask[row1] != 0);
  const int aoff = lk * 8;                        // f32 elems within 64-col step
  const float* pA0 = emb + (size_t)row0 * EMB + aoff;
  const float* pA1 = emb + (size_t)row1 * EMB + aoff;
  const float* pE0 = ext + (size_t)row0 * 64 + aoff;
  const float* pE1 = ext + (size_t)row1 * 64 + aoff;

  // ---- W staging addresses ----
  const char* wsrc = (const char*)wqp + (size_t)ttile * (NSTEP * WIMG)
                   + wid * 1024 + lane * 16;      // per-lane global source
  char* lbase = (char*)ldsW;                      // dest: uniform base (+lane*16 by HW)

  // ---- swizzled ds_read addresses ----
  const int swz0 = (lk * 16) ^ ((lr & 7) << 4);
  const int swz1 = (64 + lk * 16) ^ ((lr & 7) << 4);
  const int rbase = (wt + lr) * 128;              // + tf*2048 (+ buf*16384)

  f32x4 acc[2][4];
#pragma unroll
  for (int m = 0; m < 2; ++m)
#pragma unroll
    for (int t = 0; t < 4; ++t)
      acc[m][t] = (f32x4){0.f, 0.f, 0.f, 0.f};

  float4 Aa[2][2][2], Ab[2][2][2];                // [rowgrp][kk][half]

  auto stageW = [&](int s, int buf) {
    const char* g = wsrc + (size_t)s * WIMG;
    char* l = lbase + buf * WIMG + wid * 1024;
#pragma unroll
    for (int j = 0; j < 4; ++j)
      g2l16(g + j * 4096, l + j * 4096);
  };

  auto loadA = [&](int s, float4 (&A)[2][2][2]) {
    const float* p0;
    const float* p1;
    if (s < NSTEP - 1) { p0 = pA0 + s * 64; p1 = pA1 + s * 64; }
    else               { p0 = pE0;          p1 = pE1; }
    if (m0) {
#pragma unroll
      for (int kk = 0; kk < 2; ++kk) {
        A[0][kk][0] = *(const float4*)(p0 + kk * 32);
        A[0][kk][1] = *(const float4*)(p0 + kk * 32 + 4);
      }
    } else {
#pragma unroll
      for (int kk = 0; kk < 2; ++kk)
        A[0][kk][0] = A[0][kk][1] = make_float4(0.f, 0.f, 0.f, 0.f);
    }
    if (m1) {
#pragma unroll
      for (int kk = 0; kk < 2; ++kk) {
        A[1][kk][0] = *(const float4*)(p1 + kk * 32);
        A[1][kk][1] = *(const float4*)(p1 + kk * 32 + 4);
      }
    } else {
#pragma unroll
      for (int kk = 0; kk < 2; ++kk)
        A[1][kk][0] = A[1][kk][1] = make_float4(0.f, 0.f, 0.f, 0.f);
    }
  };

  auto compute = [&](int buf, const float4 (&A)[2][2][2]) {
    const char* l = lbase + buf * WIMG;
#pragma unroll
    for (int kk = 0; kk < 2; ++kk) {
      bf16x8 a0 = cvt8(A[0][kk][0], A[0][kk][1]);
      bf16x8 a1 = cvt8(A[1][kk][0], A[1][kk][1]);
      const int sw = kk ? swz1 : swz0;
#pragma unroll
      for (int tf = 0; tf < 4; ++tf) {
        bf16x8 bv = *(const bf16x8*)(l + rbase + tf * 2048 + sw);
        acc[0][tf] = __builtin_amdgcn_mfma_f32_16x16x32_bf16(a0, bv, acc[0][tf], 0, 0, 0);
        acc[1][tf] = __builtin_amdgcn_mfma_f32_16x16x32_bf16(a1, bv, acc[1][tf], 0, 0, 0);
      }
    }
  };

  // prologue
  stageW(0, 0);
  loadA(0, Aa);
  __syncthreads();

#pragma unroll 1
  for (int s = 0; s < NSTEP - 1; s += 2) {   // s = 0,2,...,46
    stageW(s + 1, 1);
    loadA(s + 1, Ab);
    compute(0, Aa);
    __syncthreads();
    stageW(s + 2, 0);
    loadA(s + 2, Aa);
    compute(1, Ab);
    __syncthreads();
  }
  compute(0, Aa);                            // step 48 (staged into buf0 at s=46)

  // epilogue: D col = lane&15 (t), row = (lane>>4)*4 + r (m)
#pragma unroll
  for (int tf = 0; tf < 4; ++tf) {
    const int t = tBase + wt + tf * 16 + lr;
    const float bv = bias[t];
#pragma unroll
    for (int mf = 0; mf < 2; ++mf) {
#pragma unroll
      for (int r = 0; r < 4; ++r) {
        const int bn = mBase + wm + mf * 16 + lk * 4 + r;
        out[(size_t)bn * TDIM + t] = (mask[bn] != 0) ? (acc[mf][tf][r] + bv) : 0.f;
      }
    }
  }
}

extern "C" void kernel_launch(void* const* d_in, const int* in_sizes, int n_in,
                              void* d_out, int out_size, void* d_ws, size_t ws_size,
                              hipStream_t stream) {
  const float* emb   = (const float*)d_in[0];
  const float* vis   = (const float*)d_in[1];
  const float* bbox  = (const float*)d_in[2];
  const float* kpt   = (const float*)d_in[3];
  const int*   mask  = (const int*)d_in[4];   // jnp.bool_ -> int32 per harness contract
  const float* W     = (const float*)d_in[5];
  const float* bias  = (const float*)d_in[6];
  float* out = (float*)d_out;

  // ws: [ ext f32 16384*64 = 4MB ][ wq bf16 2*49*8192 = 1.57MB ]
  float* ext          = (float*)d_ws;
  unsigned short* wq  = (unsigned short*)((char*)d_ws + (size_t)TOKENS * 64 * 4);

  pack_w_kernel  <<<(2 * NSTEP * 8192 + 255) / 256, 256, 0, stream>>>(W, wq);
  pack_ext_kernel<<<(TOKENS * 64) / 256,            256, 0, stream>>>(vis, bbox, kpt, ext);
  linproj_kernel <<<512, 256, 0, stream>>>(emb, mask, wq, ext, bias, out);
}